// Round 5
// baseline (532.224 us; speedup 1.0000x reference)
//
#include <hip/hip_runtime.h>
#include <stdint.h>
#include <stddef.h>

#define LSEQ   2048
#define DMODEL 2048
#define NH     32
#define DINNER 2048
#define PROJ   8224
#define PROJP  8320   // 65 * 128
#define NC     16     // scan chunks
#define CHUNK  128    // LSEQ / NC

typedef __attribute__((ext_vector_type(4))) float f32x4;
typedef __attribute__((ext_vector_type(8))) __bf16 bf16x8;
typedef __attribute__((ext_vector_type(8))) unsigned short u16x8;

__device__ __forceinline__ unsigned short f2bf(float f) {
  union { float f; unsigned u; } uu; uu.f = f;
  unsigned r = uu.u + 0x7FFFu + ((uu.u >> 16) & 1u);
  return (unsigned short)(r >> 16);
}
__device__ __forceinline__ float bf2f(unsigned short u) {
  union { unsigned u; float f; } x; x.u = ((unsigned)u) << 16; return x.f;
}
__device__ __forceinline__ void ld_bf8(const unsigned short* p, f32x4& a, f32x4& b) {
  u16x8 v = *(const u16x8*)p;
  a[0] = bf2f(v[0]); a[1] = bf2f(v[1]); a[2] = bf2f(v[2]); a[3] = bf2f(v[3]);
  b[0] = bf2f(v[4]); b[1] = bf2f(v[5]); b[2] = bf2f(v[6]); b[3] = bf2f(v[7]);
}

__device__ __forceinline__ void gl_lds16(const void* g, void* l) {
  __builtin_amdgcn_global_load_lds(
      (__attribute__((address_space(1))) const void*)g,
      (__attribute__((address_space(3))) void*)l, 16, 0, 0);
}

// ---------------- conversions ----------------
__global__ __launch_bounds__(256) void cvt_f32_bf16(
    const float* __restrict__ in, unsigned short* __restrict__ out, int n) {
  int i = (blockIdx.x * 256 + threadIdx.x) * 4;
  if (i + 3 < n) {
    f32x4 v = *(const f32x4*)(in + i);
    ushort4 o;
    o.x = f2bf(v[0]); o.y = f2bf(v[1]); o.z = f2bf(v[2]); o.w = f2bf(v[3]);
    *(ushort4*)(out + i) = o;
  }
}

// W_in [8224,2048] f32 -> bf16 padded to [8320,2048] (pad rows = 0)
__global__ __launch_bounds__(256) void cvt_win(
    const float* __restrict__ w, unsigned short* __restrict__ out) {
  int i = (blockIdx.x * 256 + threadIdx.x) * 4;   // < 8320*2048
  int row = i >> 11;
  ushort4 o = {0, 0, 0, 0};
  if (row < PROJ) {
    f32x4 v = *(const f32x4*)(w + i);
    o.x = f2bf(v[0]); o.y = f2bf(v[1]); o.z = f2bf(v[2]); o.w = f2bf(v[3]);
  }
  *(ushort4*)(out + i) = o;
}

// ---------------- bf16 NT GEMM: C[M,N] = A[M,K] * W[N,K]^T ----------------
// 128x128 tile, BK=32, 4 waves (2x2). 4-slot LDS ring, 3-tiles-ahead
// prefetch with counted vmcnt(12) (loads span ~3 compute windows), raw
// s_barrier. GM=4 grouped (m,n) mapping under bijective XCD swizzle.
// obf!=0 -> store C as bf16, else fp32.
__global__ __launch_bounds__(256) void gemm_bt(
    const unsigned short* __restrict__ A,
    const unsigned short* __restrict__ W,
    void* __restrict__ Cv, const int K, const int ldc, const int ntx,
    const int obf) {
  __shared__ uint8_t sA[4][8192];
  __shared__ uint8_t sB[4][8192];
  const int tid  = threadIdx.x;
  const int lane = tid & 63;
  const int wid  = tid >> 6;
  const int wm   = wid >> 1;
  const int wn   = wid & 1;
  // XCD bijective remap (grid % 8 == 0), then GM=4 grouped mapping:
  // 4 consecutive blocks share an N-panel; 4 M-rows cycle within an XCD.
  const int nwg = gridDim.x;
  const int wg0 = blockIdx.x;
  const int g   = (wg0 & 7) * (nwg >> 3) + (wg0 >> 3);
  const int grp = ntx * 4;
  const int sr  = g / grp, rem = g % grp;
  const int m0  = (sr * 4 + (rem & 3)) * 128;
  const int n0  = (rem >> 2) * 128;

  // staging: LDS linear dest (wave-uniform base + lane*16); source k-slot
  // pre-swizzled so that LDS[row][slot^swz(row)] holds (row,slot).
  // BK=32 -> 64-byte rows, swz(row) = (row>>1)&3 (2-way bank alias = free).
  const int rowA = tid >> 2;                       // 0..63 (+ j*64)
  const int slot = (tid & 3) ^ ((tid >> 3) & 3);
  const unsigned short* a_base = A + (size_t)(m0 + rowA) * K + slot * 8;
  const unsigned short* b_base = W + (size_t)(n0 + rowA) * K + slot * 8;
  const int wb = wid * 1024;

  f32x4 acc[4][4] = {};
  const int nk = K >> 5;                           // BK=32

#define STAGE(t) do { const int _b = (t) & 3;                                 \
    const unsigned short* _a = a_base + (size_t)(t) * 32;                     \
    const unsigned short* _w = b_base + (size_t)(t) * 32;                     \
    gl_lds16(_a,                    &sA[_b][wb]);                             \
    gl_lds16(_a + 64 * (size_t)K,   &sA[_b][4096 + wb]);                      \
    gl_lds16(_w,                    &sB[_b][wb]);                             \
    gl_lds16(_w + 64 * (size_t)K,   &sB[_b][4096 + wb]); } while (0)

  STAGE(0); STAGE(1); STAGE(2);

  for (int t = 0; t < nk; ++t) {
    const int cur = t & 3;
    if (t + 3 < nk) {
      STAGE(t + 3);                                  // slot (t+3)&3: last read at t-1
      asm volatile("s_waitcnt vmcnt(12)" ::: "memory"); // oldest 4 = tile t
    } else if (t + 2 < nk) {
      asm volatile("s_waitcnt vmcnt(8)" ::: "memory");
    } else if (t + 1 < nk) {
      asm volatile("s_waitcnt vmcnt(4)" ::: "memory");
    } else {
      asm volatile("s_waitcnt vmcnt(0)" ::: "memory");
    }
    asm volatile("s_barrier" ::: "memory");          // tile t visible to all waves

    const int ra = wm * 64 + (lane & 15);
    const int rb = wn * 64 + (lane & 15);
    const int s  = lane >> 4;                        // k-slot 0..3
    bf16x8 af[4], bv[4];
#pragma unroll
    for (int mi = 0; mi < 4; ++mi) {
      const int r = ra + mi * 16;
      af[mi] = *(const bf16x8*)(&sA[cur][r * 64 + ((s ^ ((r >> 1) & 3)) << 4)]);
    }
#pragma unroll
    for (int ni = 0; ni < 4; ++ni) {
      const int r = rb + ni * 16;
      bv[ni] = *(const bf16x8*)(&sB[cur][r * 64 + ((s ^ ((r >> 1) & 3)) << 4)]);
    }
#pragma unroll
    for (int mi = 0; mi < 4; ++mi)
#pragma unroll
      for (int ni = 0; ni < 4; ++ni)
        acc[mi][ni] = __builtin_amdgcn_mfma_f32_16x16x32_bf16(
            af[mi], bv[ni], acc[mi][ni], 0, 0, 0);

    asm volatile("s_barrier" ::: "memory");          // reads done before re-stage
  }
#undef STAGE

  // epilogue: D mapping col=lane&15, row=(lane>>4)*4+reg
  const int crow = m0 + wm * 64 + (lane >> 4) * 4;
  const int ccol = n0 + wn * 64 + (lane & 15);
  if (obf) {
    unsigned short* C = (unsigned short*)Cv;
#pragma unroll
    for (int mi = 0; mi < 4; ++mi)
#pragma unroll
      for (int ni = 0; ni < 4; ++ni) {
        unsigned short* cp = C + (size_t)(crow + mi * 16) * ldc + ccol + ni * 16;
        cp[0] = f2bf(acc[mi][ni][0]);
        cp[(size_t)ldc] = f2bf(acc[mi][ni][1]);
        cp[2 * (size_t)ldc] = f2bf(acc[mi][ni][2]);
        cp[3 * (size_t)ldc] = f2bf(acc[mi][ni][3]);
      }
  } else {
    float* C = (float*)Cv;
#pragma unroll
    for (int mi = 0; mi < 4; ++mi)
#pragma unroll
      for (int ni = 0; ni < 4; ++ni) {
        float* cp = C + (size_t)(crow + mi * 16) * ldc + ccol + ni * 16;
        cp[0] = acc[mi][ni][0];
        cp[(size_t)ldc] = acc[mi][ni][1];
        cp[2 * (size_t)ldc] = acc[mi][ni][2];
        cp[3 * (size_t)ldc] = acc[mi][ni][3];
      }
  }
}

// ---------------- exact fp32 a_log slab: Alog[4096,32] = x * W_a^T ----------------
#define AR  64
#define AKT 128
__global__ __launch_bounds__(256) void alog_part(
    const float* __restrict__ x, const float* __restrict__ W_in,
    float* __restrict__ P) {
  __shared__ float sX[AR][132];
  __shared__ float sW[32][132];
  const int tid = threadIdx.x;
  const int row0 = blockIdx.x * AR;
  const int k0 = blockIdx.y * 256;
  const int r = tid >> 2;          // 0..63
  const int oq = (tid & 3) * 8;    // col group
  float acc[8] = {};
#pragma unroll
  for (int kt = 0; kt < 256; kt += AKT) {
    __syncthreads();
    {
      const int lr = tid >> 2;
      const int kk = (tid & 3) * 32;
      const float* src = x + (size_t)(row0 + lr) * DMODEL + k0 + kt + kk;
      float* dst = &sX[lr][kk];
#pragma unroll
      for (int j = 0; j < 32; j += 4)
        *(f32x4*)(dst + j) = *(const f32x4*)(src + j);
    }
    {
      const int wr = tid >> 3;     // 0..31
      const int kk = (tid & 7) * 16;
      const float* src = W_in + (size_t)(8192 + wr) * DMODEL + k0 + kt + kk;
      float* dst = &sW[wr][kk];
#pragma unroll
      for (int j = 0; j < 16; j += 4)
        *(f32x4*)(dst + j) = *(const f32x4*)(src + j);
    }
    __syncthreads();
#pragma unroll 2
    for (int k = 0; k < AKT; k += 4) {
      f32x4 xv = *(const f32x4*)&sX[r][k];
#pragma unroll
      for (int o = 0; o < 8; ++o) {
        f32x4 wv = *(const f32x4*)&sW[oq + o][k];
        acc[o] = fmaf(xv[0], wv[0], acc[o]);
        acc[o] = fmaf(xv[1], wv[1], acc[o]);
        acc[o] = fmaf(xv[2], wv[2], acc[o]);
        acc[o] = fmaf(xv[3], wv[3], acc[o]);
      }
    }
  }
  float* dst = P + ((size_t)blockIdx.y * 4096 + row0 + r) * 32 + oq;
  f32x4 v0 = {acc[0], acc[1], acc[2], acc[3]};
  f32x4 v1 = {acc[4], acc[5], acc[6], acc[7]};
  *(f32x4*)dst = v0; *(f32x4*)(dst + 4) = v1;
}

__global__ __launch_bounds__(256) void alog_reduce(
    const float* __restrict__ P, float* __restrict__ Alog) {
  const int idx = blockIdx.x * 256 + threadIdx.x;  // 0..131071
  const int row = idx >> 5, o = idx & 31;
  float s = 0.f;
#pragma unroll
  for (int c = 0; c < 8; ++c) s += P[((size_t)c * 4096 + row) * 32 + o];
  Alog[(size_t)row * 32 + o] = s;
}

// ---------------- chunked selective scan (zx in bf16, a_log in fp32) ----------------
// vblk (0..511): pq = vblk&7, bh = vblk>>3; lane owns p=pq*8+(lane&7),
// states n = nc..nc+7 where nc = (lane>>3)*8. 4 waves per 256-thr block.

__global__ __launch_bounds__(256) void scan_pass1(
    const unsigned short* __restrict__ zx, const float* __restrict__ Alog,
    float* __restrict__ Sfin, float* __restrict__ Dprod) {
  const int lane = threadIdx.x & 63;
  const int vblk = blockIdx.x * 4 + (threadIdx.x >> 6);
  const int pq = vblk & 7;
  const int bh = vblk >> 3;
  const int h = bh & (NH - 1);
  const int b = bh >> 5;
  const int chunk = blockIdx.y;
  const int p = pq * 8 + (lane & 7);
  const int nc = (lane >> 3) << 3;

  const unsigned short* base = zx + (size_t)b * LSEQ * PROJP;
  const float* abase = Alog + (size_t)b * LSEQ * 32 + h;
  const int xoff = h * 64 + p;
  const int boff = 4096 + h * 64 + nc;
  const int l0 = chunk * CHUNK, lend = l0 + CHUNK;

  float s0 = 0, s1 = 0, s2 = 0, s3 = 0, s4 = 0, s5 = 0, s6 = 0, s7 = 0;
  float dp = 1.f;

  f32x4 pba, pbb; float pxv, pav;
  f32x4 nba, nbb; float nxv, nav;
  const unsigned short* r0 = base + (size_t)l0 * PROJP;
  ld_bf8(r0 + boff, pba, pbb);
  pxv = bf2f(r0[xoff]); pav = abase[(size_t)l0 * 32];

  for (int l = l0; l < lend; l += 2) {
    const unsigned short* r1 = base + (size_t)(l + 1) * PROJP;
    ld_bf8(r1 + boff, nba, nbb);
    nxv = bf2f(r1[xoff]); nav = abase[(size_t)(l + 1) * 32];

    {
      float dec = __expf(-__expf(pav)); dp *= dec;
      s0 = fmaf(s0, dec, pxv * pba[0]); s1 = fmaf(s1, dec, pxv * pba[1]);
      s2 = fmaf(s2, dec, pxv * pba[2]); s3 = fmaf(s3, dec, pxv * pba[3]);
      s4 = fmaf(s4, dec, pxv * pbb[0]); s5 = fmaf(s5, dec, pxv * pbb[1]);
      s6 = fmaf(s6, dec, pxv * pbb[2]); s7 = fmaf(s7, dec, pxv * pbb[3]);
    }
    if (l + 2 < lend) {
      const unsigned short* r2 = base + (size_t)(l + 2) * PROJP;
      ld_bf8(r2 + boff, pba, pbb);
      pxv = bf2f(r2[xoff]); pav = abase[(size_t)(l + 2) * 32];
    }
    {
      float dec = __expf(-__expf(nav)); dp *= dec;
      s0 = fmaf(s0, dec, nxv * nba[0]); s1 = fmaf(s1, dec, nxv * nba[1]);
      s2 = fmaf(s2, dec, nxv * nba[2]); s3 = fmaf(s3, dec, nxv * nba[3]);
      s4 = fmaf(s4, dec, nxv * nbb[0]); s5 = fmaf(s5, dec, nxv * nbb[1]);
      s6 = fmaf(s6, dec, nxv * nbb[2]); s7 = fmaf(s7, dec, nxv * nbb[3]);
    }
  }

  float* sf = Sfin + ((size_t)bh * NC + chunk) * 4096 + p * 64 + nc;
  f32x4 va = {s0, s1, s2, s3}, vb = {s4, s5, s6, s7};
  *(f32x4*)sf = va; *(f32x4*)(sf + 4) = vb;
  if (lane == 0) Dprod[bh * NC + chunk] = dp;
}

// Combine: exclusive prefix over chunks -> per-chunk initial states.
__global__ __launch_bounds__(256) void scan_combine(
    const float* __restrict__ Sfin, const float* __restrict__ Dp,
    float* __restrict__ Sini) {
  const int idx = blockIdx.x * 256 + threadIdx.x;   // 0..262143
  const int bh = idx >> 12;
  const int e = idx & 4095;
  const float* sf = Sfin + (size_t)bh * NC * 4096 + e;
  float* si = Sini + (size_t)bh * NC * 4096 + e;
  float S = 0.f;
#pragma unroll
  for (int c = 0; c < NC; ++c) {
    si[(size_t)c * 4096] = S;
    if (c < NC - 1) S = fmaf(S, Dp[bh * NC + c], sf[(size_t)c * 4096]);
  }
}

// Pass 2: scan chunk from its true initial state, emit y.
#define SCAN_STEP(BA, BB, CA, CB, XV, AV, LIDX) do {                          \
    float dec_ = __expf(-__expf(AV));                                         \
    float y0_ = 0.f, y1_ = 0.f;                                               \
    s0 = fmaf(s0, dec_, (XV) * (BA)[0]); y0_ = fmaf(s0, (CA)[0], y0_);        \
    s1 = fmaf(s1, dec_, (XV) * (BA)[1]); y1_ = fmaf(s1, (CA)[1], y1_);        \
    s2 = fmaf(s2, dec_, (XV) * (BA)[2]); y0_ = fmaf(s2, (CA)[2], y0_);        \
    s3 = fmaf(s3, dec_, (XV) * (BA)[3]); y1_ = fmaf(s3, (CA)[3], y1_);        \
    s4 = fmaf(s4, dec_, (XV) * (BB)[0]); y0_ = fmaf(s4, (CB)[0], y0_);        \
    s5 = fmaf(s5, dec_, (XV) * (BB)[1]); y1_ = fmaf(s5, (CB)[1], y1_);        \
    s6 = fmaf(s6, dec_, (XV) * (BB)[2]); y0_ = fmaf(s6, (CB)[2], y0_);        \
    s7 = fmaf(s7, dec_, (XV) * (BB)[3]); y1_ = fmaf(s7, (CB)[3], y1_);        \
    float yy_ = y0_ + y1_;                                                    \
    yy_ += __shfl_xor(yy_, 8);                                                \
    yy_ += __shfl_xor(yy_, 16);                                               \
    yy_ += __shfl_xor(yy_, 32);                                               \
    if (lane < 8) yout[(size_t)(LIDX) * DINNER] = yy_ + (XV) * dDv;           \
  } while (0)

__global__ __launch_bounds__(256) void scan_pass2(
    const unsigned short* __restrict__ zx, const float* __restrict__ Alog,
    const float* __restrict__ Dmat, const float* __restrict__ Sini,
    float* __restrict__ y) {
  const int lane = threadIdx.x & 63;
  const int vblk = blockIdx.x * 4 + (threadIdx.x >> 6);
  const int pq = vblk & 7;
  const int bh = vblk >> 3;
  const int h = bh & (NH - 1);
  const int b = bh >> 5;
  const int chunk = blockIdx.y;
  const int p = pq * 8 + (lane & 7);
  const int nc = (lane >> 3) << 3;

  const unsigned short* base = zx + (size_t)b * LSEQ * PROJP;
  const float* abase = Alog + (size_t)b * LSEQ * 32 + h;
  const int xoff = h * 64 + p;
  const int boff = 4096 + h * 64 + nc;
  const int coff = 6144 + h * 64 + nc;
  const float dDv = Dmat[h * 64 + p];
  float* yout = y + (size_t)b * LSEQ * DINNER + h * 64 + p;
  const int l0 = chunk * CHUNK, lend = l0 + CHUNK;

  const float* si = Sini + ((size_t)bh * NC + chunk) * 4096 + p * 64 + nc;
  f32x4 sva = *(const f32x4*)si, svb = *(const f32x4*)(si + 4);
  float s0 = sva[0], s1 = sva[1], s2 = sva[2], s3 = sva[3];
  float s4 = svb[0], s5 = svb[1], s6 = svb[2], s7 = svb[3];

  f32x4 pba, pbb, pca, pcb; float pxv, pav;
  f32x4 nba, nbb, nca, ncb; float nxv, nav;
  const unsigned short* r0 = base + (size_t)l0 * PROJP;
  ld_bf8(r0 + boff, pba, pbb); ld_bf8(r0 + coff, pca, pcb);
  pxv = bf2f(r0[xoff]); pav = abase[(size_t)l0 * 32];

  for (int l = l0; l < lend; l += 2) {
    const unsigned short* r1 = base + (size_t)(l + 1) * PROJP;
    ld_bf8(r1 + boff, nba, nbb); ld_bf8(r1 + coff, nca, ncb);
    nxv = bf2f(r1[xoff]); nav = abase[(size_t)(l + 1) * 32];

    SCAN_STEP(pba, pbb, pca, pcb, pxv, pav, l);

    if (l + 2 < lend) {
      const unsigned short* r2 = base + (size_t)(l + 2) * PROJP;
      ld_bf8(r2 + boff, pba, pbb); ld_bf8(r2 + coff, pca, pcb);
      pxv = bf2f(r2[xoff]); pav = abase[(size_t)(l + 2) * 32];
    }

    SCAN_STEP(nba, nbb, nca, ncb, nxv, nav, l + 1);
  }
}

// ---------------- fused silu(z)*y + LayerNorm -> bf16 ----------------
__global__ __launch_bounds__(256) void siluln(
    const float* __restrict__ yin, const unsigned short* __restrict__ zx,
    const float* __restrict__ gamma, const float* __restrict__ beta,
    unsigned short* __restrict__ out) {
  const int row = blockIdx.x;
  const int tid = threadIdx.x;
  const int lane = tid & 63;
  const int wid = tid >> 6;
  const int col = tid * 8;
  const float* yp = yin + (size_t)row * DINNER + col;
  const unsigned short* zp = zx + (size_t)row * PROJP + DINNER + col;
  f32x4 y0 = *(const f32x4*)yp, y1 = *(const f32x4*)(yp + 4);
  u16x8 zv = *(const u16x8*)zp;
  float v[8];
#pragma unroll
  for (int i = 0; i < 8; ++i) {
    float z = bf2f(zv[i]);
    float yy = (i < 4) ? y0[i] : y1[i - 4];
    v[i] = yy * (z / (1.f + __expf(-z)));
  }
  float t1 = 0.f, t2 = 0.f;
#pragma unroll
  for (int i = 0; i < 8; ++i) { t1 += v[i]; t2 += v[i] * v[i]; }
#pragma unroll
  for (int off = 1; off < 64; off <<= 1) {
    t1 += __shfl_xor(t1, off);
    t2 += __shfl_xor(t2, off);
  }
  __shared__ float red[8];
  if (lane == 0) { red[wid] = t1; red[wid + 4] = t2; }
  __syncthreads();
  float ts1 = red[0] + red[1] + red[2] + red[3];
  float ts2 = red[4] + red[5] + red[6] + red[7];
  float mu = ts1 * (1.f / 2048.f);
  float var = ts2 * (1.f / 2048.f) - mu * mu;
  float rs = rsqrtf(var + 1e-5f);
  f32x4 g0 = *(const f32x4*)(gamma + col), g1 = *(const f32x4*)(gamma + col + 4);
  f32x4 b0 = *(const f32x4*)(beta + col),  b1 = *(const f32x4*)(beta + col + 4);
  u16x8 ov;
#pragma unroll
  for (int i = 0; i < 4; ++i)
    ov[i] = f2bf((v[i] - mu) * rs * g0[i] + b0[i]);
#pragma unroll
  for (int i = 0; i < 4; ++i)
    ov[i + 4] = f2bf((v[i + 4] - mu) * rs * g1[i] + b1[i]);
  *(u16x8*)(out + (size_t)row * DINNER + col) = ov;
}

// ---------------- launch ----------------
extern "C" void kernel_launch(void* const* d_in, const int* in_sizes, int n_in,
                              void* d_out, int out_size, void* d_ws, size_t ws_size,
                              hipStream_t stream) {
  (void)in_sizes; (void)n_in; (void)out_size; (void)ws_size;
  const float* x     = (const float*)d_in[0];
  const float* W_in  = (const float*)d_in[1];
  const float* W_out = (const float*)d_in[2];
  const float* gamma = (const float*)d_in[3];
  const float* beta  = (const float*)d_in[4];
  const float* Dmat  = (const float*)d_in[5];

  uint8_t* ws = (uint8_t*)d_ws;
  unsigned short* xbf = (unsigned short*)ws;                 // 16 MB; later y_ln
  unsigned short* wbf = (unsigned short*)(ws + 16777216);    // 34 MB region (W)
  // scratch carved from wbf region (dead between gemm1 and cvt W_out):
  float* Palog = (float*)(ws + 16777216);                    // 4 MB
  float* Sfin  = (float*)(ws + 16777216);                    // 16.78 MB (after alog)
  float* Sini  = (float*)(ws + 33554432);                    // 16.78 MB
  float* Dprod = (float*)(ws + 50331648);                    // 4 KB
  float* Alog  = (float*)(ws + 50855936);                    // 512 KB (persists)
  unsigned short* zxb = (unsigned short*)(ws + 51380224);    // 68.2 MB (bf16)
  float* ybuf = (float*)(ws + 119537664);                    // 33.6 MB

  cvt_f32_bf16<<<8192, 256, 0, stream>>>(x, xbf, 8388608);
  cvt_win<<<16640, 256, 0, stream>>>(W_in, wbf);
  gemm_bt<<<2080, 256, 0, stream>>>(xbf, wbf, zxb, 2048, PROJP, 65, 1);
  alog_part<<<dim3(64, 8), 256, 0, stream>>>(x, W_in, Palog);
  alog_reduce<<<512, 256, 0, stream>>>(Palog, Alog);
  scan_pass1<<<dim3(128, NC - 1), 256, 0, stream>>>(zxb, Alog, Sfin, Dprod);
  scan_combine<<<1024, 256, 0, stream>>>(Sfin, Dprod, Sini);
  scan_pass2<<<dim3(128, NC), 256, 0, stream>>>(zxb, Alog, Dmat, Sini, ybuf);
  siluln<<<4096, 256, 0, stream>>>(ybuf, zxb, gamma, beta, xbf);
  cvt_f32_bf16<<<4096, 256, 0, stream>>>(W_out, wbf, 4194304);
  gemm_bt<<<512, 256, 0, stream>>>(xbf, wbf, (float*)d_out, 2048, 2048, 16, 0);
}

// Round 6
// 483.282 us; speedup vs baseline: 1.1013x; 1.1013x over previous
//
#include <hip/hip_runtime.h>
#include <stdint.h>
#include <stddef.h>

#define LSEQ   2048
#define DMODEL 2048
#define NH     32
#define DINNER 2048
#define PROJ   8224
#define PROJP  8320   // 65 * 128
#define NC     16     // scan chunks
#define CHUNK  128    // LSEQ / NC

typedef __attribute__((ext_vector_type(4))) float f32x4;
typedef __attribute__((ext_vector_type(8))) __bf16 bf16x8;
typedef __attribute__((ext_vector_type(8))) unsigned short u16x8;

__device__ __forceinline__ unsigned short f2bf(float f) {
  union { float f; unsigned u; } uu; uu.f = f;
  unsigned r = uu.u + 0x7FFFu + ((uu.u >> 16) & 1u);
  return (unsigned short)(r >> 16);
}
__device__ __forceinline__ float bf2f(unsigned short u) {
  union { unsigned u; float f; } x; x.u = ((unsigned)u) << 16; return x.f;
}
__device__ __forceinline__ void ld_bf8(const unsigned short* p, f32x4& a, f32x4& b) {
  u16x8 v = *(const u16x8*)p;
  a[0] = bf2f(v[0]); a[1] = bf2f(v[1]); a[2] = bf2f(v[2]); a[3] = bf2f(v[3]);
  b[0] = bf2f(v[4]); b[1] = bf2f(v[5]); b[2] = bf2f(v[6]); b[3] = bf2f(v[7]);
}

__device__ __forceinline__ void gl_lds16(const void* g, void* l) {
  __builtin_amdgcn_global_load_lds(
      (__attribute__((address_space(1))) const void*)g,
      (__attribute__((address_space(3))) void*)l, 16, 0, 0);
}

// ---------------- conversions ----------------
__global__ __launch_bounds__(256) void cvt_f32_bf16(
    const float* __restrict__ in, unsigned short* __restrict__ out, int n) {
  int i = (blockIdx.x * 256 + threadIdx.x) * 4;
  if (i + 3 < n) {
    f32x4 v = *(const f32x4*)(in + i);
    ushort4 o;
    o.x = f2bf(v[0]); o.y = f2bf(v[1]); o.z = f2bf(v[2]); o.w = f2bf(v[3]);
    *(ushort4*)(out + i) = o;
  }
}

// W_in [8224,2048] f32 -> bf16 padded to [8320,2048] (pad rows = 0)
__global__ __launch_bounds__(256) void cvt_win(
    const float* __restrict__ w, unsigned short* __restrict__ out) {
  int i = (blockIdx.x * 256 + threadIdx.x) * 4;   // < 8320*2048
  int row = i >> 11;
  ushort4 o = {0, 0, 0, 0};
  if (row < PROJ) {
    f32x4 v = *(const f32x4*)(w + i);
    o.x = f2bf(v[0]); o.y = f2bf(v[1]); o.z = f2bf(v[2]); o.w = f2bf(v[3]);
  }
  *(ushort4*)(out + i) = o;
}

// ---------------- bf16 NT GEMM: C[M,N] = A[M,K] * W[N,K]^T ----------------
// 128x128 tile, BK=64, 4 waves (2x2). Round-4 verified pipeline: 2-slot LDS
// double-buffer, counted vmcnt(8), raw s_barrier. Round-5 verified GM=4
// grouped (m,n) mapping under bijective XCD swizzle (FETCH 548->174 MB).
// obf!=0 -> store C as bf16, else fp32.
__global__ __launch_bounds__(256) void gemm_bt(
    const unsigned short* __restrict__ A,
    const unsigned short* __restrict__ W,
    void* __restrict__ Cv, const int K, const int ldc, const int ntx,
    const int obf) {
  __shared__ uint8_t sA[2][128 * 64 * 2];
  __shared__ uint8_t sB[2][128 * 64 * 2];
  const int tid  = threadIdx.x;
  const int lane = tid & 63;
  const int wid  = tid >> 6;
  const int wm   = wid >> 1;
  const int wn   = wid & 1;
  // XCD bijective remap (grid % 8 == 0), then GM=4 grouped mapping:
  // 4 consecutive blocks share an N-panel; 4 M-rows cycle within an XCD.
  const int nwg = gridDim.x;
  const int wg0 = blockIdx.x;
  const int g   = (wg0 & 7) * (nwg >> 3) + (wg0 >> 3);
  const int grp = ntx * 4;
  const int sr  = g / grp, rem = g % grp;
  const int m0  = (sr * 4 + (rem & 3)) * 128;
  const int n0  = (rem >> 2) * 128;

  // staging: LDS linear dest (lane*16); source k-slot XOR-swizzled by row&7
  const int rowA = tid >> 3;                      // 0..31 (+ j*32)
  const int slot = (tid & 7) ^ (rowA & 7);
  const unsigned short* a_base = A + (size_t)(m0 + rowA) * K + slot * 8;
  const unsigned short* b_base = W + (size_t)(n0 + rowA) * K + slot * 8;
  const int loff = wid * 1024;

  f32x4 acc[4][4] = {};
  const int nk = K >> 6;

  // prologue: fill buffer 0 with tile 0
#pragma unroll
  for (int j = 0; j < 4; ++j) {
    gl_lds16(a_base + (size_t)j * 32 * K, &sA[0][loff + j * 4096]);
    gl_lds16(b_base + (size_t)j * 32 * K, &sB[0][loff + j * 4096]);
  }

  for (int kt = 0; kt < nk; ++kt) {
    const int cur = kt & 1;
    if (kt + 1 < nk) {
      // issue next tile's loads into the other buffer (stay in flight
      // across this tile's compute)
      const unsigned short* ak = a_base + (kt + 1) * 64;
      const unsigned short* bk = b_base + (kt + 1) * 64;
      const int nb = cur ^ 1;
#pragma unroll
      for (int j = 0; j < 4; ++j) {
        gl_lds16(ak + (size_t)j * 32 * K, &sA[nb][loff + j * 4096]);
        gl_lds16(bk + (size_t)j * 32 * K, &sB[nb][loff + j * 4096]);
      }
      asm volatile("s_waitcnt vmcnt(8)" ::: "memory");  // oldest 8 = buf[cur] fill
    } else {
      asm volatile("s_waitcnt vmcnt(0)" ::: "memory");
    }
    asm volatile("s_barrier" ::: "memory");  // buf[cur] ready on all waves

    const int ra = wm * 64 + (lane & 15);
    const int rb = wn * 64 + (lane & 15);
    const int hq = lane >> 4;
#pragma unroll
    for (int ks = 0; ks < 2; ++ks) {
      bf16x8 af[4], bv[4];
      const int s = ks * 4 + hq;
#pragma unroll
      for (int mi = 0; mi < 4; ++mi) {
        const int r = ra + mi * 16;
        af[mi] = *(const bf16x8*)(&sA[cur][r * 128 + ((s ^ (r & 7)) << 4)]);
      }
#pragma unroll
      for (int ni = 0; ni < 4; ++ni) {
        const int r = rb + ni * 16;
        bv[ni] = *(const bf16x8*)(&sB[cur][r * 128 + ((s ^ (r & 7)) << 4)]);
      }
#pragma unroll
      for (int mi = 0; mi < 4; ++mi)
#pragma unroll
        for (int ni = 0; ni < 4; ++ni)
          acc[mi][ni] = __builtin_amdgcn_mfma_f32_16x16x32_bf16(
              af[mi], bv[ni], acc[mi][ni], 0, 0, 0);
    }
    // all waves done reading buf[cur] before next iter overwrites it
    asm volatile("s_barrier" ::: "memory");
  }

  // epilogue: D mapping col=lane&15, row=(lane>>4)*4+reg
  const int crow = m0 + wm * 64 + (lane >> 4) * 4;
  const int ccol = n0 + wn * 64 + (lane & 15);
  if (obf) {
    unsigned short* C = (unsigned short*)Cv;
#pragma unroll
    for (int mi = 0; mi < 4; ++mi)
#pragma unroll
      for (int ni = 0; ni < 4; ++ni) {
        unsigned short* cp = C + (size_t)(crow + mi * 16) * ldc + ccol + ni * 16;
        cp[0] = f2bf(acc[mi][ni][0]);
        cp[(size_t)ldc] = f2bf(acc[mi][ni][1]);
        cp[2 * (size_t)ldc] = f2bf(acc[mi][ni][2]);
        cp[3 * (size_t)ldc] = f2bf(acc[mi][ni][3]);
      }
  } else {
    float* C = (float*)Cv;
#pragma unroll
    for (int mi = 0; mi < 4; ++mi)
#pragma unroll
      for (int ni = 0; ni < 4; ++ni) {
        float* cp = C + (size_t)(crow + mi * 16) * ldc + ccol + ni * 16;
        cp[0] = acc[mi][ni][0];
        cp[(size_t)ldc] = acc[mi][ni][1];
        cp[2 * (size_t)ldc] = acc[mi][ni][2];
        cp[3 * (size_t)ldc] = acc[mi][ni][3];
      }
  }
}

// ---------------- exact fp32 a_log slab: Alog[4096,32] = x * W_a^T ----------------
#define AR  64
#define AKT 128
__global__ __launch_bounds__(256) void alog_part(
    const float* __restrict__ x, const float* __restrict__ W_in,
    float* __restrict__ P) {
  __shared__ float sX[AR][132];
  __shared__ float sW[32][132];
  const int tid = threadIdx.x;
  const int row0 = blockIdx.x * AR;
  const int k0 = blockIdx.y * 256;
  const int r = tid >> 2;          // 0..63
  const int oq = (tid & 3) * 8;    // col group
  float acc[8] = {};
#pragma unroll
  for (int kt = 0; kt < 256; kt += AKT) {
    __syncthreads();
    {
      const int lr = tid >> 2;
      const int kk = (tid & 3) * 32;
      const float* src = x + (size_t)(row0 + lr) * DMODEL + k0 + kt + kk;
      float* dst = &sX[lr][kk];
#pragma unroll
      for (int j = 0; j < 32; j += 4)
        *(f32x4*)(dst + j) = *(const f32x4*)(src + j);
    }
    {
      const int wr = tid >> 3;     // 0..31
      const int kk = (tid & 7) * 16;
      const float* src = W_in + (size_t)(8192 + wr) * DMODEL + k0 + kt + kk;
      float* dst = &sW[wr][kk];
#pragma unroll
      for (int j = 0; j < 16; j += 4)
        *(f32x4*)(dst + j) = *(const f32x4*)(src + j);
    }
    __syncthreads();
#pragma unroll 2
    for (int k = 0; k < AKT; k += 4) {
      f32x4 xv = *(const f32x4*)&sX[r][k];
#pragma unroll
      for (int o = 0; o < 8; ++o) {
        f32x4 wv = *(const f32x4*)&sW[oq + o][k];
        acc[o] = fmaf(xv[0], wv[0], acc[o]);
        acc[o] = fmaf(xv[1], wv[1], acc[o]);
        acc[o] = fmaf(xv[2], wv[2], acc[o]);
        acc[o] = fmaf(xv[3], wv[3], acc[o]);
      }
    }
  }
  float* dst = P + ((size_t)blockIdx.y * 4096 + row0 + r) * 32 + oq;
  f32x4 v0 = {acc[0], acc[1], acc[2], acc[3]};
  f32x4 v1 = {acc[4], acc[5], acc[6], acc[7]};
  *(f32x4*)dst = v0; *(f32x4*)(dst + 4) = v1;
}

__global__ __launch_bounds__(256) void alog_reduce(
    const float* __restrict__ P, float* __restrict__ Alog) {
  const int idx = blockIdx.x * 256 + threadIdx.x;  // 0..131071
  const int row = idx >> 5, o = idx & 31;
  float s = 0.f;
#pragma unroll
  for (int c = 0; c < 8; ++c) s += P[((size_t)c * 4096 + row) * 32 + o];
  Alog[(size_t)row * 32 + o] = s;
}

// ---------------- chunked selective scan (zx in bf16, a_log in fp32) ----------------
// vblk (0..511): pq = vblk&7, bh = vblk>>3; lane owns p=pq*8+(lane&7),
// states n = nc..nc+7 where nc = (lane>>3)*8. 4 waves per 256-thr block.

__global__ __launch_bounds__(256) void scan_pass1(
    const unsigned short* __restrict__ zx, const float* __restrict__ Alog,
    float* __restrict__ Sfin, float* __restrict__ Dprod) {
  const int lane = threadIdx.x & 63;
  const int vblk = blockIdx.x * 4 + (threadIdx.x >> 6);
  const int pq = vblk & 7;
  const int bh = vblk >> 3;
  const int h = bh & (NH - 1);
  const int b = bh >> 5;
  const int chunk = blockIdx.y;
  const int p = pq * 8 + (lane & 7);
  const int nc = (lane >> 3) << 3;

  const unsigned short* base = zx + (size_t)b * LSEQ * PROJP;
  const float* abase = Alog + (size_t)b * LSEQ * 32 + h;
  const int xoff = h * 64 + p;
  const int boff = 4096 + h * 64 + nc;
  const int l0 = chunk * CHUNK, lend = l0 + CHUNK;

  float s0 = 0, s1 = 0, s2 = 0, s3 = 0, s4 = 0, s5 = 0, s6 = 0, s7 = 0;
  float dp = 1.f;

  f32x4 pba, pbb; float pxv, pav;
  f32x4 nba, nbb; float nxv, nav;
  const unsigned short* r0 = base + (size_t)l0 * PROJP;
  ld_bf8(r0 + boff, pba, pbb);
  pxv = bf2f(r0[xoff]); pav = abase[(size_t)l0 * 32];

  for (int l = l0; l < lend; l += 2) {
    const unsigned short* r1 = base + (size_t)(l + 1) * PROJP;
    ld_bf8(r1 + boff, nba, nbb);
    nxv = bf2f(r1[xoff]); nav = abase[(size_t)(l + 1) * 32];

    {
      float dec = __expf(-__expf(pav)); dp *= dec;
      s0 = fmaf(s0, dec, pxv * pba[0]); s1 = fmaf(s1, dec, pxv * pba[1]);
      s2 = fmaf(s2, dec, pxv * pba[2]); s3 = fmaf(s3, dec, pxv * pba[3]);
      s4 = fmaf(s4, dec, pxv * pbb[0]); s5 = fmaf(s5, dec, pxv * pbb[1]);
      s6 = fmaf(s6, dec, pxv * pbb[2]); s7 = fmaf(s7, dec, pxv * pbb[3]);
    }
    if (l + 2 < lend) {
      const unsigned short* r2 = base + (size_t)(l + 2) * PROJP;
      ld_bf8(r2 + boff, pba, pbb);
      pxv = bf2f(r2[xoff]); pav = abase[(size_t)(l + 2) * 32];
    }
    {
      float dec = __expf(-__expf(nav)); dp *= dec;
      s0 = fmaf(s0, dec, nxv * nba[0]); s1 = fmaf(s1, dec, nxv * nba[1]);
      s2 = fmaf(s2, dec, nxv * nba[2]); s3 = fmaf(s3, dec, nxv * nba[3]);
      s4 = fmaf(s4, dec, nxv * nbb[0]); s5 = fmaf(s5, dec, nxv * nbb[1]);
      s6 = fmaf(s6, dec, nxv * nbb[2]); s7 = fmaf(s7, dec, nxv * nbb[3]);
    }
  }

  float* sf = Sfin + ((size_t)bh * NC + chunk) * 4096 + p * 64 + nc;
  f32x4 va = {s0, s1, s2, s3}, vb = {s4, s5, s6, s7};
  *(f32x4*)sf = va; *(f32x4*)(sf + 4) = vb;
  if (lane == 0) Dprod[bh * NC + chunk] = dp;
}

// Combine: exclusive prefix over chunks -> per-chunk initial states.
__global__ __launch_bounds__(256) void scan_combine(
    const float* __restrict__ Sfin, const float* __restrict__ Dp,
    float* __restrict__ Sini) {
  const int idx = blockIdx.x * 256 + threadIdx.x;   // 0..262143
  const int bh = idx >> 12;
  const int e = idx & 4095;
  const float* sf = Sfin + (size_t)bh * NC * 4096 + e;
  float* si = Sini + (size_t)bh * NC * 4096 + e;
  float S = 0.f;
#pragma unroll
  for (int c = 0; c < NC; ++c) {
    si[(size_t)c * 4096] = S;
    if (c < NC - 1) S = fmaf(S, Dp[bh * NC + c], sf[(size_t)c * 4096]);
  }
}

// Pass 2: scan chunk from its true initial state, emit y.
#define SCAN_STEP(BA, BB, CA, CB, XV, AV, LIDX) do {                          \
    float dec_ = __expf(-__expf(AV));                                         \
    float y0_ = 0.f, y1_ = 0.f;                                               \
    s0 = fmaf(s0, dec_, (XV) * (BA)[0]); y0_ = fmaf(s0, (CA)[0], y0_);        \
    s1 = fmaf(s1, dec_, (XV) * (BA)[1]); y1_ = fmaf(s1, (CA)[1], y1_);        \
    s2 = fmaf(s2, dec_, (XV) * (BA)[2]); y0_ = fmaf(s2, (CA)[2], y0_);        \
    s3 = fmaf(s3, dec_, (XV) * (BA)[3]); y1_ = fmaf(s3, (CA)[3], y1_);        \
    s4 = fmaf(s4, dec_, (XV) * (BB)[0]); y0_ = fmaf(s4, (CB)[0], y0_);        \
    s5 = fmaf(s5, dec_, (XV) * (BB)[1]); y1_ = fmaf(s5, (CB)[1], y1_);        \
    s6 = fmaf(s6, dec_, (XV) * (BB)[2]); y0_ = fmaf(s6, (CB)[2], y0_);        \
    s7 = fmaf(s7, dec_, (XV) * (BB)[3]); y1_ = fmaf(s7, (CB)[3], y1_);        \
    float yy_ = y0_ + y1_;                                                    \
    yy_ += __shfl_xor(yy_, 8);                                                \
    yy_ += __shfl_xor(yy_, 16);                                               \
    yy_ += __shfl_xor(yy_, 32);                                               \
    if (lane < 8) yout[(size_t)(LIDX) * DINNER] = yy_ + (XV) * dDv;           \
  } while (0)

__global__ __launch_bounds__(256) void scan_pass2(
    const unsigned short* __restrict__ zx, const float* __restrict__ Alog,
    const float* __restrict__ Dmat, const float* __restrict__ Sini,
    float* __restrict__ y) {
  const int lane = threadIdx.x & 63;
  const int vblk = blockIdx.x * 4 + (threadIdx.x >> 6);
  const int pq = vblk & 7;
  const int bh = vblk >> 3;
  const int h = bh & (NH - 1);
  const int b = bh >> 5;
  const int chunk = blockIdx.y;
  const int p = pq * 8 + (lane & 7);
  const int nc = (lane >> 3) << 3;

  const unsigned short* base = zx + (size_t)b * LSEQ * PROJP;
  const float* abase = Alog + (size_t)b * LSEQ * 32 + h;
  const int xoff = h * 64 + p;
  const int boff = 4096 + h * 64 + nc;
  const int coff = 6144 + h * 64 + nc;
  const float dDv = Dmat[h * 64 + p];
  float* yout = y + (size_t)b * LSEQ * DINNER + h * 64 + p;
  const int l0 = chunk * CHUNK, lend = l0 + CHUNK;

  const float* si = Sini + ((size_t)bh * NC + chunk) * 4096 + p * 64 + nc;
  f32x4 sva = *(const f32x4*)si, svb = *(const f32x4*)(si + 4);
  float s0 = sva[0], s1 = sva[1], s2 = sva[2], s3 = sva[3];
  float s4 = svb[0], s5 = svb[1], s6 = svb[2], s7 = svb[3];

  f32x4 pba, pbb, pca, pcb; float pxv, pav;
  f32x4 nba, nbb, nca, ncb; float nxv, nav;
  const unsigned short* r0 = base + (size_t)l0 * PROJP;
  ld_bf8(r0 + boff, pba, pbb); ld_bf8(r0 + coff, pca, pcb);
  pxv = bf2f(r0[xoff]); pav = abase[(size_t)l0 * 32];

  for (int l = l0; l < lend; l += 2) {
    const unsigned short* r1 = base + (size_t)(l + 1) * PROJP;
    ld_bf8(r1 + boff, nba, nbb); ld_bf8(r1 + coff, nca, ncb);
    nxv = bf2f(r1[xoff]); nav = abase[(size_t)(l + 1) * 32];

    SCAN_STEP(pba, pbb, pca, pcb, pxv, pav, l);

    if (l + 2 < lend) {
      const unsigned short* r2 = base + (size_t)(l + 2) * PROJP;
      ld_bf8(r2 + boff, pba, pbb); ld_bf8(r2 + coff, pca, pcb);
      pxv = bf2f(r2[xoff]); pav = abase[(size_t)(l + 2) * 32];
    }

    SCAN_STEP(nba, nbb, nca, ncb, nxv, nav, l + 1);
  }
}

// ---------------- fused silu(z)*y + LayerNorm -> bf16 ----------------
__global__ __launch_bounds__(256) void siluln(
    const float* __restrict__ yin, const unsigned short* __restrict__ zx,
    const float* __restrict__ gamma, const float* __restrict__ beta,
    unsigned short* __restrict__ out) {
  const int row = blockIdx.x;
  const int tid = threadIdx.x;
  const int lane = tid & 63;
  const int wid = tid >> 6;
  const int col = tid * 8;
  const float* yp = yin + (size_t)row * DINNER + col;
  const unsigned short* zp = zx + (size_t)row * PROJP + DINNER + col;
  f32x4 y0 = *(const f32x4*)yp, y1 = *(const f32x4*)(yp + 4);
  u16x8 zv = *(const u16x8*)zp;
  float v[8];
#pragma unroll
  for (int i = 0; i < 8; ++i) {
    float z = bf2f(zv[i]);
    float yy = (i < 4) ? y0[i] : y1[i - 4];
    v[i] = yy * (z / (1.f + __expf(-z)));
  }
  float t1 = 0.f, t2 = 0.f;
#pragma unroll
  for (int i = 0; i < 8; ++i) { t1 += v[i]; t2 += v[i] * v[i]; }
#pragma unroll
  for (int off = 1; off < 64; off <<= 1) {
    t1 += __shfl_xor(t1, off);
    t2 += __shfl_xor(t2, off);
  }
  __shared__ float red[8];
  if (lane == 0) { red[wid] = t1; red[wid + 4] = t2; }
  __syncthreads();
  float ts1 = red[0] + red[1] + red[2] + red[3];
  float ts2 = red[4] + red[5] + red[6] + red[7];
  float mu = ts1 * (1.f / 2048.f);
  float var = ts2 * (1.f / 2048.f) - mu * mu;
  float rs = rsqrtf(var + 1e-5f);
  f32x4 g0 = *(const f32x4*)(gamma + col), g1 = *(const f32x4*)(gamma + col + 4);
  f32x4 b0 = *(const f32x4*)(beta + col),  b1 = *(const f32x4*)(beta + col + 4);
  u16x8 ov;
#pragma unroll
  for (int i = 0; i < 4; ++i)
    ov[i] = f2bf((v[i] - mu) * rs * g0[i] + b0[i]);
#pragma unroll
  for (int i = 0; i < 4; ++i)
    ov[i + 4] = f2bf((v[i + 4] - mu) * rs * g1[i] + b1[i]);
  *(u16x8*)(out + (size_t)row * DINNER + col) = ov;
}

// ---------------- launch ----------------
extern "C" void kernel_launch(void* const* d_in, const int* in_sizes, int n_in,
                              void* d_out, int out_size, void* d_ws, size_t ws_size,
                              hipStream_t stream) {
  (void)in_sizes; (void)n_in; (void)out_size; (void)ws_size;
  const float* x     = (const float*)d_in[0];
  const float* W_in  = (const float*)d_in[1];
  const float* W_out = (const float*)d_in[2];
  const float* gamma = (const float*)d_in[3];
  const float* beta  = (const float*)d_in[4];
  const float* Dmat  = (const float*)d_in[5];

  uint8_t* ws = (uint8_t*)d_ws;
  unsigned short* xbf = (unsigned short*)ws;                 // 16 MB; later y_ln
  unsigned short* wbf = (unsigned short*)(ws + 16777216);    // 34 MB region (W)
  // scratch carved from wbf region (dead between gemm1 and cvt W_out):
  float* Palog = (float*)(ws + 16777216);                    // 4 MB
  float* Sfin  = (float*)(ws + 16777216);                    // 16.78 MB (after alog)
  float* Sini  = (float*)(ws + 33554432);                    // 16.78 MB
  float* Dprod = (float*)(ws + 50331648);                    // 4 KB
  float* Alog  = (float*)(ws + 50855936);                    // 512 KB (persists)
  unsigned short* zxb = (unsigned short*)(ws + 51380224);    // 68.2 MB (bf16)
  float* ybuf = (float*)(ws + 119537664);                    // 33.6 MB

  cvt_f32_bf16<<<8192, 256, 0, stream>>>(x, xbf, 8388608);
  cvt_win<<<16640, 256, 0, stream>>>(W_in, wbf);
  gemm_bt<<<2080, 256, 0, stream>>>(xbf, wbf, zxb, 2048, PROJP, 65, 1);
  alog_part<<<dim3(64, 8), 256, 0, stream>>>(x, W_in, Palog);
  alog_reduce<<<512, 256, 0, stream>>>(Palog, Alog);
  scan_pass1<<<dim3(128, NC - 1), 256, 0, stream>>>(zxb, Alog, Sfin, Dprod);
  scan_combine<<<1024, 256, 0, stream>>>(Sfin, Dprod, Sini);
  scan_pass2<<<dim3(128, NC), 256, 0, stream>>>(zxb, Alog, Dmat, Sini, ybuf);
  siluln<<<4096, 256, 0, stream>>>(ybuf, zxb, gamma, beta, xbf);
  cvt_f32_bf16<<<4096, 256, 0, stream>>>(W_out, wbf, 4194304);
  gemm_bt<<<512, 256, 0, stream>>>(xbf, wbf, (float*)d_out, 2048, 2048, 16, 0);
}

// Round 7
// 453.159 us; speedup vs baseline: 1.1745x; 1.0665x over previous
//
#include <hip/hip_runtime.h>
#include <stdint.h>
#include <stddef.h>

#define LSEQ   2048
#define DMODEL 2048
#define NH     32
#define DINNER 2048
#define PROJ   8224
#define PROJP  8192   // bf16 GEMM width: x,z,b,c only (a_log handled in fp32)
#define NC     16     // scan chunks
#define CHUNK  128    // LSEQ / NC

typedef __attribute__((ext_vector_type(4))) float f32x4;
typedef __attribute__((ext_vector_type(8))) __bf16 bf16x8;
typedef __attribute__((ext_vector_type(8))) unsigned short u16x8;

__device__ __forceinline__ unsigned short f2bf(float f) {
  union { float f; unsigned u; } uu; uu.f = f;
  unsigned r = uu.u + 0x7FFFu + ((uu.u >> 16) & 1u);
  return (unsigned short)(r >> 16);
}
__device__ __forceinline__ float bf2f(unsigned short u) {
  union { unsigned u; float f; } x; x.u = ((unsigned)u) << 16; return x.f;
}
__device__ __forceinline__ void ld_bf8(const unsigned short* p, f32x4& a, f32x4& b) {
  u16x8 v = *(const u16x8*)p;
  a[0] = bf2f(v[0]); a[1] = bf2f(v[1]); a[2] = bf2f(v[2]); a[3] = bf2f(v[3]);
  b[0] = bf2f(v[4]); b[1] = bf2f(v[5]); b[2] = bf2f(v[6]); b[3] = bf2f(v[7]);
}

__device__ __forceinline__ void gl_lds16(const void* g, void* l) {
  __builtin_amdgcn_global_load_lds(
      (__attribute__((address_space(1))) const void*)g,
      (__attribute__((address_space(3))) void*)l, 16, 0, 0);
}

// ---------------- conversions ----------------
__global__ __launch_bounds__(256) void cvt_f32_bf16(
    const float* __restrict__ in, unsigned short* __restrict__ out, int n) {
  int i = (blockIdx.x * 256 + threadIdx.x) * 4;
  if (i + 3 < n) {
    f32x4 v = *(const f32x4*)(in + i);
    ushort4 o;
    o.x = f2bf(v[0]); o.y = f2bf(v[1]); o.z = f2bf(v[2]); o.w = f2bf(v[3]);
    *(ushort4*)(out + i) = o;
  }
}

// ---------------- 256x256 bf16 NT GEMM (gemm1): C[M,8192] = A * W^T ----------------
// BK=64, 8 waves (2Mx4N), 2-slot LDS (128 KB, 1 block/CU). ONE s_barrier and
// ONE vmcnt(0) per K-tile: {wait kt landed; barrier (== all waves done with
// kt-1, so slot (kt+1)&1 is free); stage kt+1; compute kt}. Fragment/swizzle/
// C-write math identical to the verified 128-tile kernel. bf16 output.
__global__ __launch_bounds__(512, 2) void gemm256(
    const unsigned short* __restrict__ A,
    const unsigned short* __restrict__ W,
    unsigned short* __restrict__ C, const int K, const int ldc, const int ntx) {
  __shared__ uint8_t sA[2][32768];
  __shared__ uint8_t sB[2][32768];
  const int tid  = threadIdx.x;
  const int lane = tid & 63;
  const int wid  = tid >> 6;       // 0..7
  const int wm   = wid >> 2;       // 0..1 -> rows wm*128..+128
  const int wn   = wid & 3;        // 0..3 -> cols wn*64..+64
  // XCD bijective remap + GM=4 grouped mapping (round-5/6 verified).
  const int nwg = gridDim.x;
  const int wg0 = blockIdx.x;
  const int g   = (wg0 & 7) * (nwg >> 3) + (wg0 >> 3);
  const int grp = ntx * 4;
  const int sr  = g / grp, rem = g % grp;
  const int m0  = (sr * 4 + (rem & 3)) * 256;
  const int n0  = (rem >> 2) * 256;

  // staging: linear LDS dest (wave-uniform + lane*16); source slot swizzled.
  // dst byte = j*8192 + wid*1024 + lane*16  ->  row = j*64+wid*8+(lane>>3),
  // slot = lane&7; src col-slot = slot ^ (row&7)  (row&7 == (lane>>3)&7).
  const int row0 = wid * 8 + (lane >> 3);
  const int ssrc = (lane & 7) ^ (row0 & 7);
  const unsigned short* a_base = A + (size_t)(m0 + row0) * K + ssrc * 8;
  const unsigned short* b_base = W + (size_t)(n0 + row0) * K + ssrc * 8;
  const int wb = wid * 1024;

  f32x4 acc[8][4] = {};
  const int nk = K >> 6;

#define STG(t) do { const int _s = (t) & 1;                                   \
    const unsigned short* _a = a_base + (size_t)(t) * 64;                     \
    const unsigned short* _w = b_base + (size_t)(t) * 64;                     \
    _Pragma("unroll")                                                         \
    for (int j = 0; j < 4; ++j) {                                             \
      gl_lds16(_a + (size_t)j * 64 * K, &sA[_s][j * 8192 + wb]);              \
      gl_lds16(_w + (size_t)j * 64 * K, &sB[_s][j * 8192 + wb]);              \
    } } while (0)

  STG(0);

  for (int kt = 0; kt < nk; ++kt) {
    const int cur = kt & 1;
    asm volatile("s_waitcnt vmcnt(0)" ::: "memory");   // kt's fill landed
    asm volatile("s_barrier" ::: "memory");            // all waves: kt ready, kt-1 slot free
    if (kt + 1 < nk) STG(kt + 1);

    const int ra = wm * 128 + (lane & 15);
    const int rb = wn * 64 + (lane & 15);
    const int hq = lane >> 4;
#pragma unroll
    for (int ks = 0; ks < 2; ++ks) {
      const int s = ks * 4 + hq;
      bf16x8 af[8], bv[4];
#pragma unroll
      for (int mi = 0; mi < 8; ++mi) {
        const int r = ra + mi * 16;
        af[mi] = *(const bf16x8*)(&sA[cur][r * 128 + ((s ^ (r & 7)) << 4)]);
      }
#pragma unroll
      for (int ni = 0; ni < 4; ++ni) {
        const int r = rb + ni * 16;
        bv[ni] = *(const bf16x8*)(&sB[cur][r * 128 + ((s ^ (r & 7)) << 4)]);
      }
#pragma unroll
      for (int mi = 0; mi < 8; ++mi)
#pragma unroll
        for (int ni = 0; ni < 4; ++ni)
          acc[mi][ni] = __builtin_amdgcn_mfma_f32_16x16x32_bf16(
              af[mi], bv[ni], acc[mi][ni], 0, 0, 0);
    }
  }
#undef STG

  const int crow = m0 + wm * 128 + (lane >> 4) * 4;
  const int ccol = n0 + wn * 64 + (lane & 15);
#pragma unroll
  for (int mi = 0; mi < 8; ++mi)
#pragma unroll
    for (int ni = 0; ni < 4; ++ni) {
      unsigned short* cp = C + (size_t)(crow + mi * 16) * ldc + ccol + ni * 16;
      cp[0] = f2bf(acc[mi][ni][0]);
      cp[(size_t)ldc] = f2bf(acc[mi][ni][1]);
      cp[2 * (size_t)ldc] = f2bf(acc[mi][ni][2]);
      cp[3 * (size_t)ldc] = f2bf(acc[mi][ni][3]);
    }
}

// ---------------- 128x128 bf16 NT GEMM (gemm2), single-barrier loop ----------------
__global__ __launch_bounds__(256) void gemm_bt(
    const unsigned short* __restrict__ A,
    const unsigned short* __restrict__ W,
    float* __restrict__ C, const int K, const int ldc, const int ntx) {
  __shared__ uint8_t sA[2][128 * 64 * 2];
  __shared__ uint8_t sB[2][128 * 64 * 2];
  const int tid  = threadIdx.x;
  const int lane = tid & 63;
  const int wid  = tid >> 6;
  const int wm   = wid >> 1;
  const int wn   = wid & 1;
  const int nwg = gridDim.x;
  const int wg0 = blockIdx.x;
  const int g   = (wg0 & 7) * (nwg >> 3) + (wg0 >> 3);
  const int grp = ntx * 4;
  const int sr  = g / grp, rem = g % grp;
  const int m0  = (sr * 4 + (rem & 3)) * 128;
  const int n0  = (rem >> 2) * 128;

  const int rowA = tid >> 3;
  const int slot = (tid & 7) ^ (rowA & 7);
  const unsigned short* a_base = A + (size_t)(m0 + rowA) * K + slot * 8;
  const unsigned short* b_base = W + (size_t)(n0 + rowA) * K + slot * 8;
  const int loff = wid * 1024;

  f32x4 acc[4][4] = {};
  const int nk = K >> 6;

#pragma unroll
  for (int j = 0; j < 4; ++j) {
    gl_lds16(a_base + (size_t)j * 32 * K, &sA[0][loff + j * 4096]);
    gl_lds16(b_base + (size_t)j * 32 * K, &sB[0][loff + j * 4096]);
  }

  for (int kt = 0; kt < nk; ++kt) {
    const int cur = kt & 1;
    asm volatile("s_waitcnt vmcnt(0)" ::: "memory");
    asm volatile("s_barrier" ::: "memory");
    if (kt + 1 < nk) {
      const unsigned short* ak = a_base + (kt + 1) * 64;
      const unsigned short* bk = b_base + (kt + 1) * 64;
      const int nb = cur ^ 1;
#pragma unroll
      for (int j = 0; j < 4; ++j) {
        gl_lds16(ak + (size_t)j * 32 * K, &sA[nb][loff + j * 4096]);
        gl_lds16(bk + (size_t)j * 32 * K, &sB[nb][loff + j * 4096]);
      }
    }

    const int ra = wm * 64 + (lane & 15);
    const int rb = wn * 64 + (lane & 15);
    const int hq = lane >> 4;
#pragma unroll
    for (int ks = 0; ks < 2; ++ks) {
      bf16x8 af[4], bv[4];
      const int s = ks * 4 + hq;
#pragma unroll
      for (int mi = 0; mi < 4; ++mi) {
        const int r = ra + mi * 16;
        af[mi] = *(const bf16x8*)(&sA[cur][r * 128 + ((s ^ (r & 7)) << 4)]);
      }
#pragma unroll
      for (int ni = 0; ni < 4; ++ni) {
        const int r = rb + ni * 16;
        bv[ni] = *(const bf16x8*)(&sB[cur][r * 128 + ((s ^ (r & 7)) << 4)]);
      }
#pragma unroll
      for (int mi = 0; mi < 4; ++mi)
#pragma unroll
        for (int ni = 0; ni < 4; ++ni)
          acc[mi][ni] = __builtin_amdgcn_mfma_f32_16x16x32_bf16(
              af[mi], bv[ni], acc[mi][ni], 0, 0, 0);
    }
  }

  const int crow = m0 + wm * 64 + (lane >> 4) * 4;
  const int ccol = n0 + wn * 64 + (lane & 15);
#pragma unroll
  for (int mi = 0; mi < 4; ++mi)
#pragma unroll
    for (int ni = 0; ni < 4; ++ni) {
      float* cp = C + (size_t)(crow + mi * 16) * ldc + ccol + ni * 16;
      cp[0] = acc[mi][ni][0];
      cp[(size_t)ldc] = acc[mi][ni][1];
      cp[2 * (size_t)ldc] = acc[mi][ni][2];
      cp[3 * (size_t)ldc] = acc[mi][ni][3];
    }
}

// ---------------- exact fp32 a_log slab: Alog[4096,32] = x * W_a^T ----------------
#define AR  64
#define AKT 128
__global__ __launch_bounds__(256) void alog_part(
    const float* __restrict__ x, const float* __restrict__ W_in,
    float* __restrict__ P) {
  __shared__ float sX[AR][132];
  __shared__ float sW[32][132];
  const int tid = threadIdx.x;
  const int row0 = blockIdx.x * AR;
  const int k0 = blockIdx.y * 256;
  const int r = tid >> 2;
  const int oq = (tid & 3) * 8;
  float acc[8] = {};
#pragma unroll
  for (int kt = 0; kt < 256; kt += AKT) {
    __syncthreads();
    {
      const int lr = tid >> 2;
      const int kk = (tid & 3) * 32;
      const float* src = x + (size_t)(row0 + lr) * DMODEL + k0 + kt + kk;
      float* dst = &sX[lr][kk];
#pragma unroll
      for (int j = 0; j < 32; j += 4)
        *(f32x4*)(dst + j) = *(const f32x4*)(src + j);
    }
    {
      const int wr = tid >> 3;
      const int kk = (tid & 7) * 16;
      const float* src = W_in + (size_t)(8192 + wr) * DMODEL + k0 + kt + kk;
      float* dst = &sW[wr][kk];
#pragma unroll
      for (int j = 0; j < 16; j += 4)
        *(f32x4*)(dst + j) = *(const f32x4*)(src + j);
    }
    __syncthreads();
#pragma unroll 2
    for (int k = 0; k < AKT; k += 4) {
      f32x4 xv = *(const f32x4*)&sX[r][k];
#pragma unroll
      for (int o = 0; o < 8; ++o) {
        f32x4 wv = *(const f32x4*)&sW[oq + o][k];
        acc[o] = fmaf(xv[0], wv[0], acc[o]);
        acc[o] = fmaf(xv[1], wv[1], acc[o]);
        acc[o] = fmaf(xv[2], wv[2], acc[o]);
        acc[o] = fmaf(xv[3], wv[3], acc[o]);
      }
    }
  }
  float* dst = P + ((size_t)blockIdx.y * 4096 + row0 + r) * 32 + oq;
  f32x4 v0 = {acc[0], acc[1], acc[2], acc[3]};
  f32x4 v1 = {acc[4], acc[5], acc[6], acc[7]};
  *(f32x4*)dst = v0; *(f32x4*)(dst + 4) = v1;
}

__global__ __launch_bounds__(256) void alog_reduce(
    const float* __restrict__ P, float* __restrict__ Alog) {
  const int idx = blockIdx.x * 256 + threadIdx.x;
  const int row = idx >> 5, o = idx & 31;
  float s = 0.f;
#pragma unroll
  for (int c = 0; c < 8; ++c) s += P[((size_t)c * 4096 + row) * 32 + o];
  Alog[(size_t)row * 32 + o] = s;
}

// ---------------- chunked selective scan (zx bf16 stride 8192, a_log fp32) --------
__global__ __launch_bounds__(256) void scan_pass1(
    const unsigned short* __restrict__ zx, const float* __restrict__ Alog,
    float* __restrict__ Sfin, float* __restrict__ Dprod) {
  const int lane = threadIdx.x & 63;
  const int vblk = blockIdx.x * 4 + (threadIdx.x >> 6);
  const int pq = vblk & 7;
  const int bh = vblk >> 3;
  const int h = bh & (NH - 1);
  const int b = bh >> 5;
  const int chunk = blockIdx.y;
  const int p = pq * 8 + (lane & 7);
  const int nc = (lane >> 3) << 3;

  const unsigned short* base = zx + (size_t)b * LSEQ * PROJP;
  const float* abase = Alog + (size_t)b * LSEQ * 32 + h;
  const int xoff = h * 64 + p;
  const int boff = 4096 + h * 64 + nc;
  const int l0 = chunk * CHUNK, lend = l0 + CHUNK;

  float s0 = 0, s1 = 0, s2 = 0, s3 = 0, s4 = 0, s5 = 0, s6 = 0, s7 = 0;
  float dp = 1.f;

  f32x4 pba, pbb; float pxv, pav;
  f32x4 nba, nbb; float nxv, nav;
  const unsigned short* r0 = base + (size_t)l0 * PROJP;
  ld_bf8(r0 + boff, pba, pbb);
  pxv = bf2f(r0[xoff]); pav = abase[(size_t)l0 * 32];

  for (int l = l0; l < lend; l += 2) {
    const unsigned short* r1 = base + (size_t)(l + 1) * PROJP;
    ld_bf8(r1 + boff, nba, nbb);
    nxv = bf2f(r1[xoff]); nav = abase[(size_t)(l + 1) * 32];

    {
      float dec = __expf(-__expf(pav)); dp *= dec;
      s0 = fmaf(s0, dec, pxv * pba[0]); s1 = fmaf(s1, dec, pxv * pba[1]);
      s2 = fmaf(s2, dec, pxv * pba[2]); s3 = fmaf(s3, dec, pxv * pba[3]);
      s4 = fmaf(s4, dec, pxv * pbb[0]); s5 = fmaf(s5, dec, pxv * pbb[1]);
      s6 = fmaf(s6, dec, pxv * pbb[2]); s7 = fmaf(s7, dec, pxv * pbb[3]);
    }
    if (l + 2 < lend) {
      const unsigned short* r2 = base + (size_t)(l + 2) * PROJP;
      ld_bf8(r2 + boff, pba, pbb);
      pxv = bf2f(r2[xoff]); pav = abase[(size_t)(l + 2) * 32];
    }
    {
      float dec = __expf(-__expf(nav)); dp *= dec;
      s0 = fmaf(s0, dec, nxv * nba[0]); s1 = fmaf(s1, dec, nxv * nba[1]);
      s2 = fmaf(s2, dec, nxv * nba[2]); s3 = fmaf(s3, dec, nxv * nba[3]);
      s4 = fmaf(s4, dec, nxv * nbb[0]); s5 = fmaf(s5, dec, nxv * nbb[1]);
      s6 = fmaf(s6, dec, nxv * nbb[2]); s7 = fmaf(s7, dec, nxv * nbb[3]);
    }
  }

  float* sf = Sfin + ((size_t)bh * NC + chunk) * 4096 + p * 64 + nc;
  f32x4 va = {s0, s1, s2, s3}, vb = {s4, s5, s6, s7};
  *(f32x4*)sf = va; *(f32x4*)(sf + 4) = vb;
  if (lane == 0) Dprod[bh * NC + chunk] = dp;
}

__global__ __launch_bounds__(256) void scan_combine(
    const float* __restrict__ Sfin, const float* __restrict__ Dp,
    float* __restrict__ Sini) {
  const int idx = blockIdx.x * 256 + threadIdx.x;
  const int bh = idx >> 12;
  const int e = idx & 4095;
  const float* sf = Sfin + (size_t)bh * NC * 4096 + e;
  float* si = Sini + (size_t)bh * NC * 4096 + e;
  float S = 0.f;
#pragma unroll
  for (int c = 0; c < NC; ++c) {
    si[(size_t)c * 4096] = S;
    if (c < NC - 1) S = fmaf(S, Dp[bh * NC + c], sf[(size_t)c * 4096]);
  }
}

#define SCAN_STEP(BA, BB, CA, CB, XV, AV, LIDX) do {                          \
    float dec_ = __expf(-__expf(AV));                                         \
    float y0_ = 0.f, y1_ = 0.f;                                               \
    s0 = fmaf(s0, dec_, (XV) * (BA)[0]); y0_ = fmaf(s0, (CA)[0], y0_);        \
    s1 = fmaf(s1, dec_, (XV) * (BA)[1]); y1_ = fmaf(s1, (CA)[1], y1_);        \
    s2 = fmaf(s2, dec_, (XV) * (BA)[2]); y0_ = fmaf(s2, (CA)[2], y0_);        \
    s3 = fmaf(s3, dec_, (XV) * (BA)[3]); y1_ = fmaf(s3, (CA)[3], y1_);        \
    s4 = fmaf(s4, dec_, (XV) * (BB)[0]); y0_ = fmaf(s4, (CB)[0], y0_);        \
    s5 = fmaf(s5, dec_, (XV) * (BB)[1]); y1_ = fmaf(s5, (CB)[1], y1_);        \
    s6 = fmaf(s6, dec_, (XV) * (BB)[2]); y0_ = fmaf(s6, (CB)[2], y0_);        \
    s7 = fmaf(s7, dec_, (XV) * (BB)[3]); y1_ = fmaf(s7, (CB)[3], y1_);        \
    float yy_ = y0_ + y1_;                                                    \
    yy_ += __shfl_xor(yy_, 8);                                                \
    yy_ += __shfl_xor(yy_, 16);                                               \
    yy_ += __shfl_xor(yy_, 32);                                               \
    if (lane < 8) yout[(size_t)(LIDX) * DINNER] = yy_ + (XV) * dDv;           \
  } while (0)

__global__ __launch_bounds__(256) void scan_pass2(
    const unsigned short* __restrict__ zx, const float* __restrict__ Alog,
    const float* __restrict__ Dmat, const float* __restrict__ Sini,
    float* __restrict__ y) {
  const int lane = threadIdx.x & 63;
  const int vblk = blockIdx.x * 4 + (threadIdx.x >> 6);
  const int pq = vblk & 7;
  const int bh = vblk >> 3;
  const int h = bh & (NH - 1);
  const int b = bh >> 5;
  const int chunk = blockIdx.y;
  const int p = pq * 8 + (lane & 7);
  const int nc = (lane >> 3) << 3;

  const unsigned short* base = zx + (size_t)b * LSEQ * PROJP;
  const float* abase = Alog + (size_t)b * LSEQ * 32 + h;
  const int xoff = h * 64 + p;
  const int boff = 4096 + h * 64 + nc;
  const int coff = 6144 + h * 64 + nc;
  const float dDv = Dmat[h * 64 + p];
  float* yout = y + (size_t)b * LSEQ * DINNER + h * 64 + p;
  const int l0 = chunk * CHUNK, lend = l0 + CHUNK;

  const float* si = Sini + ((size_t)bh * NC + chunk) * 4096 + p * 64 + nc;
  f32x4 sva = *(const f32x4*)si, svb = *(const f32x4*)(si + 4);
  float s0 = sva[0], s1 = sva[1], s2 = sva[2], s3 = sva[3];
  float s4 = svb[0], s5 = svb[1], s6 = svb[2], s7 = svb[3];

  f32x4 pba, pbb, pca, pcb; float pxv, pav;
  f32x4 nba, nbb, nca, ncb; float nxv, nav;
  const unsigned short* r0 = base + (size_t)l0 * PROJP;
  ld_bf8(r0 + boff, pba, pbb); ld_bf8(r0 + coff, pca, pcb);
  pxv = bf2f(r0[xoff]); pav = abase[(size_t)l0 * 32];

  for (int l = l0; l < lend; l += 2) {
    const unsigned short* r1 = base + (size_t)(l + 1) * PROJP;
    ld_bf8(r1 + boff, nba, nbb); ld_bf8(r1 + coff, nca, ncb);
    nxv = bf2f(r1[xoff]); nav = abase[(size_t)(l + 1) * 32];

    SCAN_STEP(pba, pbb, pca, pcb, pxv, pav, l);

    if (l + 2 < lend) {
      const unsigned short* r2 = base + (size_t)(l + 2) * PROJP;
      ld_bf8(r2 + boff, pba, pbb); ld_bf8(r2 + coff, pca, pcb);
      pxv = bf2f(r2[xoff]); pav = abase[(size_t)(l + 2) * 32];
    }

    SCAN_STEP(nba, nbb, nca, ncb, nxv, nav, l + 1);
  }
}

// ---------------- fused silu(z)*y + LayerNorm -> bf16 ----------------
__global__ __launch_bounds__(256) void siluln(
    const float* __restrict__ yin, const unsigned short* __restrict__ zx,
    const float* __restrict__ gamma, const float* __restrict__ beta,
    unsigned short* __restrict__ out) {
  const int row = blockIdx.x;
  const int tid = threadIdx.x;
  const int lane = tid & 63;
  const int wid = tid >> 6;
  const int col = tid * 8;
  const float* yp = yin + (size_t)row * DINNER + col;
  const unsigned short* zp = zx + (size_t)row * PROJP + DINNER + col;
  f32x4 y0 = *(const f32x4*)yp, y1 = *(const f32x4*)(yp + 4);
  u16x8 zv = *(const u16x8*)zp;
  float v[8];
#pragma unroll
  for (int i = 0; i < 8; ++i) {
    float z = bf2f(zv[i]);
    float yy = (i < 4) ? y0[i] : y1[i - 4];
    v[i] = yy * (z / (1.f + __expf(-z)));
  }
  float t1 = 0.f, t2 = 0.f;
#pragma unroll
  for (int i = 0; i < 8; ++i) { t1 += v[i]; t2 += v[i] * v[i]; }
#pragma unroll
  for (int off = 1; off < 64; off <<= 1) {
    t1 += __shfl_xor(t1, off);
    t2 += __shfl_xor(t2, off);
  }
  __shared__ float red[8];
  if (lane == 0) { red[wid] = t1; red[wid + 4] = t2; }
  __syncthreads();
  float ts1 = red[0] + red[1] + red[2] + red[3];
  float ts2 = red[4] + red[5] + red[6] + red[7];
  float mu = ts1 * (1.f / 2048.f);
  float var = ts2 * (1.f / 2048.f) - mu * mu;
  float rs = rsqrtf(var + 1e-5f);
  f32x4 g0 = *(const f32x4*)(gamma + col), g1 = *(const f32x4*)(gamma + col + 4);
  f32x4 b0 = *(const f32x4*)(beta + col),  b1 = *(const f32x4*)(beta + col + 4);
  u16x8 ov;
#pragma unroll
  for (int i = 0; i < 4; ++i)
    ov[i] = f2bf((v[i] - mu) * rs * g0[i] + b0[i]);
#pragma unroll
  for (int i = 0; i < 4; ++i)
    ov[i + 4] = f2bf((v[i + 4] - mu) * rs * g1[i] + b1[i]);
  *(u16x8*)(out + (size_t)row * DINNER + col) = ov;
}

// ---------------- launch ----------------
extern "C" void kernel_launch(void* const* d_in, const int* in_sizes, int n_in,
                              void* d_out, int out_size, void* d_ws, size_t ws_size,
                              hipStream_t stream) {
  (void)in_sizes; (void)n_in; (void)out_size; (void)ws_size;
  const float* x     = (const float*)d_in[0];
  const float* W_in  = (const float*)d_in[1];
  const float* W_out = (const float*)d_in[2];
  const float* gamma = (const float*)d_in[3];
  const float* beta  = (const float*)d_in[4];
  const float* Dmat  = (const float*)d_in[5];

  uint8_t* ws = (uint8_t*)d_ws;
  unsigned short* xbf = (unsigned short*)ws;                 // 16 MB; later y_ln
  unsigned short* wbf = (unsigned short*)(ws + 16777216);    // 34 MB region (W)
  // scratch carved from wbf region (dead between gemm1 and cvt W_out):
  float* Palog = (float*)(ws + 16777216);                    // 4 MB
  float* Sfin  = (float*)(ws + 16777216);                    // 16.78 MB (after alog)
  float* Sini  = (float*)(ws + 33554432);                    // 16.78 MB
  float* Dprod = (float*)(ws + 50331648);                    // 4 KB
  float* Alog  = (float*)(ws + 50855936);                    // 512 KB (persists)
  unsigned short* zxb = (unsigned short*)(ws + 51380224);    // 64 MB (bf16, stride 8192)
  float* ybuf = (float*)(ws + 119537664);                    // 33.6 MB

  cvt_f32_bf16<<<8192, 256, 0, stream>>>(x, xbf, 8388608);
  cvt_f32_bf16<<<16384, 256, 0, stream>>>(W_in, wbf, 16777216);  // first 8192 rows
  gemm256<<<512, 512, 0, stream>>>(xbf, wbf, zxb, 2048, PROJP, 32);
  alog_part<<<dim3(64, 8), 256, 0, stream>>>(x, W_in, Palog);
  alog_reduce<<<512, 256, 0, stream>>>(Palog, Alog);
  scan_pass1<<<dim3(128, NC - 1), 256, 0, stream>>>(zxb, Alog, Sfin, Dprod);
  scan_combine<<<1024, 256, 0, stream>>>(Sfin, Dprod, Sini);
  scan_pass2<<<dim3(128, NC), 256, 0, stream>>>(zxb, Alog, Dmat, Sini, ybuf);
  siluln<<<4096, 256, 0, stream>>>(ybuf, zxb, gamma, beta, xbf);
  cvt_f32_bf16<<<4096, 256, 0, stream>>>(W_out, wbf, 4194304);
  gemm_bt<<<512, 256, 0, stream>>>(xbf, wbf, (float*)d_out, 2048, 2048, 16);
}